// Round 6
// baseline (146.890 us; speedup 1.0000x reference)
//
#include <hip/hip_runtime.h>
#include <cmath>

typedef __bf16 bf16x4v __attribute__((ext_vector_type(4)));
typedef __bf16 bf16x8 __attribute__((ext_vector_type(8)));
typedef float f32x4 __attribute__((ext_vector_type(4)));

namespace {
constexpr int kN = 16, kC = 64, kT = 512, kV = 25, kS = 3, kO = 64;
constexpr int kTV = kT * kV;  // 12800
// ws layout (bytes): xm f32[25600 f] | afrag[48][8192][16] | w3f[3][512][16]
constexpr size_t WS_AFRAG = 102400;
constexpr size_t WS_W3F = WS_AFRAG + (size_t)48 * 131072;  // 6,393,856
}  // namespace

// XsT: bf16 [col=(t*32+u) 256][c' 64] swizzled, bytes [0, 32768)
__device__ __forceinline__ int swzA(int col, int cbyte) {
  return ((col << 7) + cbyte) ^ ((col & 7) << 4);
}
// X3s: bf16 [c 64][t 8][u 32] swizzled with ((c^t)&7) XOR, bytes [32768, 65536)
__device__ __forceinline__ int swzB(int c, int t, int ubyte) {
  return 32768 + (c << 9) + (((t << 6) + ubyte) ^ ((((c ^ t) & 7)) << 4));
}

// ---- k1: xm[n,c,v] = mean_t x[n,c,t,v] (phase-class accumulation, coalesced)
__global__ __launch_bounds__(256) void k1_mean(const float* __restrict__ x,
                                               float* __restrict__ xm) {
  const int bid = blockIdx.x;  // n*64 + c
  __shared__ float part[250][4];
  const int tid = threadIdx.x;
  const float4* xg4 = (const float4*)(x + (size_t)bid * kTV);
  if (tid < 250) {
    float a0 = 0.f, a1 = 0.f, a2 = 0.f, a3 = 0.f;
    for (int j = tid; j < 3200; j += 250) {  // j%250==tid -> const v-phase
      float4 v = xg4[j];
      a0 += v.x; a1 += v.y; a2 += v.z; a3 += v.w;
    }
    part[tid][0] = a0; part[tid][1] = a1; part[tid][2] = a2; part[tid][3] = a3;
  }
  __syncthreads();
  if (tid < 25) {
    float s = 0.f;
#pragma unroll
    for (int r = 0; r < 4; ++r) {
      int q = ((tid - r + 25) % 25) * 19 % 25;
#pragma unroll
      for (int p = 0; p < 10; ++p) s += part[q + 25 * p][r];
    }
    xm[bid * 25 + tid] = s * (1.f / 512.f);
  }
}

// ---- k2: a_frag (bf16, MFMA-B order, bias/colsum folded) + w3 frags
__global__ __launch_bounds__(256) void k2_attn(
    const float* __restrict__ xm, const float* __restrict__ Ag,
    const float* __restrict__ alpha, const float* __restrict__ w1,
    const float* __restrict__ b1, const float* __restrict__ w2,
    const float* __restrict__ b2, const float* __restrict__ w3,
    const float* __restrict__ w4, const float* __restrict__ b4,
    const int* __restrict__ sparse, unsigned char* __restrict__ ws) {
  const float thr = (float)sparse[0];
  const int b = blockIdx.x;
  const int s = b >> 6, n = (b >> 2) & 15, q = b & 3;
  __shared__ float xm_l[1600];
  __shared__ float x1_l[200], x2_l[200];
  __shared__ float att_l[8 * 625];
  __shared__ float attsum_l[200];
  __shared__ float ag_l[625];
  __shared__ float acs_l[25];
  __shared__ float w4_l[512];
  const int tid = threadIdx.x;
  for (int i = tid; i < 1600; i += 256) xm_l[i] = xm[n * 1600 + i];
  for (int i = tid; i < 512; i += 256) {
    float w = w4[s * 512 + i];
    w4_l[i] = (fabsf(w) > thr) ? w : 0.f;
  }
  for (int i = tid; i < 625; i += 256) ag_l[i] = Ag[s * 625 + i];
  __syncthreads();
  for (int i = tid; i < 400; i += 256) {
    int which = i / 200, idx = i % 200, r = idx / 25, u = idx % 25;
    const float* wrow = (which == 0 ? w1 : w2) + (s * 8 + r) * 64;
    float acc = 0.f;
    for (int cc = 0; cc < 64; ++cc) {
      float w = wrow[cc];
      w = (fabsf(w) > thr) ? w : 0.f;
      acc += w * xm_l[cc * 25 + u];
    }
    acc += (which == 0 ? b1 : b2)[s * 8 + r];
    if (which == 0) x1_l[idx] = acc;
    else x2_l[idx] = acc;
  }
  __syncthreads();
  for (int i = tid; i < 8 * 625; i += 256) {
    int r = i / 625, uv = i % 625, u = uv / 25, v = uv % 25;
    att_l[i] = tanhf(x1_l[r * 25 + u] - x2_l[r * 25 + v]);
  }
  __syncthreads();
  if (tid < 200) {
    int r = tid / 25, v = tid % 25;
    float sum = 0.f;
    for (int u = 0; u < 25; ++u) sum += att_l[r * 625 + u * 25 + v];
    attsum_l[tid] = sum;
  } else if (tid < 225) {
    int v = tid - 200;
    float sum = 0.f;
    for (int u = 0; u < 25; ++u) sum += ag_l[u * 25 + v];
    acs_l[v] = sum;
  }
  __syncthreads();
  const float al = alpha[0];
  // a_ext[c][u][v]: u<25 -> a ; u==25 -> colsum(a) (bias-fold) ; u>25 -> 0
  unsigned char* afrag = ws + WS_AFRAG + (size_t)(s * 16 + n) * 131072;
  for (int slot = q * 2048 + tid; slot < (q + 1) * 2048; slot += 256) {
    int c = slot >> 7, vt = (slot >> 6) & 1, l = slot & 63;
    int v = vt * 16 + (l & 15), g = l >> 4;
    bf16x8 out;
    if (v < 25) {
      float b4v = b4[s * 64 + c];
#pragma unroll
      for (int j = 0; j < 8; ++j) {
        int u = g * 8 + j;
        float val = 0.f;
        if (u < 25) {
          float acc = 0.f;
#pragma unroll
          for (int r = 0; r < 8; ++r) acc += w4_l[c * 8 + r] * att_l[r * 625 + u * 25 + v];
          val = al * (acc + b4v) + ag_l[u * 25 + v];
        } else if (u == 25) {
          float acc = 0.f;
#pragma unroll
          for (int r = 0; r < 8; ++r) acc += w4_l[c * 8 + r] * attsum_l[r * 25 + v];
          val = al * acc + 25.f * al * b4v + acs_l[v];
        }
        out[j] = (__bf16)val;
      }
    } else {
#pragma unroll
      for (int j = 0; j < 8; ++j) out[j] = (__bf16)0.f;
    }
    *(bf16x8*)(afrag + (size_t)slot * 16) = out;
  }
  // w3 frags
  if (n == 0 && tid < 128) {
    unsigned char* w3f = ws + WS_W3F + (size_t)s * 8192;
    int slot = q * 128 + tid;
    int ot = slot >> 7, ks = (slot >> 6) & 1, l = slot & 63;
    int o = ot * 16 + (l & 15), g = l >> 4;
    bf16x8 out;
#pragma unroll
    for (int j = 0; j < 8; ++j) {
      int cp = ks * 32 + g * 8 + j;
      float w = w3[(s * 64 + o) * 64 + cp];
      out[j] = (__bf16)((fabsf(w) > thr) ? w : 0.f);
    }
    *(bf16x8*)(w3f + slot * 16) = out;
  }
}

// ---- k3: TT=8, 64 KB LDS, 2 blocks/CU. stage -> GEMM1 -> X3s -> GEMM2 -> zs -> relu
__global__ __launch_bounds__(512, 4) void k3_main(const float* __restrict__ x,
                                                  const float* __restrict__ b3,
                                                  const unsigned char* __restrict__ ws,
                                                  float* __restrict__ y) {
  const int n = blockIdx.x;   // linear%8 == n%8 -> same-n blocks share XCD
  const int tb = blockIdx.y;  // 0..63 (8-t chunks)
  extern __shared__ __align__(16) unsigned char smem[];  // 65536
  const int tid = threadIdx.x;
  const int w = tid >> 6, l = tid & 63, g = l >> 4, l15 = l & 15;
  const float4* xg4 = (const float4*)(x + (size_t)n * kC * kTV);

  // zero XsT pad cols u=25..31 (b128 granules): 56 cols x 8 chunks
  for (int idx = tid; idx < 448; idx += 512) {
    int col_i = idx >> 3, gb = idx & 7;
    int t = col_i / 7, u = 25 + col_i % 7;
    f32x4 z = {0.f, 0.f, 0.f, 0.f};
    *(f32x4*)(smem + swzA(t * 32 + u, gb * 16)) = z;
  }
  // zero X3s pad u=26..31 (3 b32 per (c,t))
  for (int idx = tid; idx < 1536; idx += 512) {
    int pair = idx / 3, k = idx % 3;
    int c = pair >> 3, t = pair & 7;
    *(unsigned int*)(smem + swzB(c, t, 52 + 4 * k)) = 0u;
  }
  // stage x f32 -> XsT bf16 (coalesced f4 reads, b16 scatter)
  for (int i4 = tid; i4 < 3200; i4 += 512) {
    int c = i4 / 50, r4 = i4 % 50;
    float4 vv = xg4[c * 3200 + tb * 50 + r4];
    float vals[4] = {vv.x, vv.y, vv.z, vv.w};
    int lin = r4 * 4;
#pragma unroll
    for (int k = 0; k < 4; ++k) {
      int t = (lin + k) / 25, u = (lin + k) % 25;
      *(__bf16*)(smem + swzA(t * 32 + u, c * 2)) = (__bf16)vals[k];
    }
  }
  __syncthreads();

  const unsigned char* afrag = ws + WS_AFRAG;
  const unsigned char* w3f = ws + WS_W3F;

  f32x4 zacc[8][2];
#pragma unroll
  for (int cc = 0; cc < 8; ++cc)
#pragma unroll
    for (int vt = 0; vt < 2; ++vt) {
      f32x4 zz = {0.f, 0.f, 0.f, 0.f};
      zacc[cc][vt] = zz;
    }

  for (int s = 0; s < kS; ++s) {
    bf16x8 A1[4][2];
#pragma unroll
    for (int ot = 0; ot < 4; ++ot)
#pragma unroll
      for (int ks = 0; ks < 2; ++ks)
        A1[ot][ks] = *(const bf16x8*)(w3f + s * 8192 + ((ot * 2 + ks) * 64 + l) * 16);
    if (s) __syncthreads();  // GEMM2(s-1) X3s reads done before scatter overwrite

    // GEMM1 (swapped): D1[col][o]; wave w owns cols [32w, 32w+32)
    f32x4 acc[2][4];
#pragma unroll
    for (int cti = 0; cti < 2; ++cti) {
      int col = w * 32 + cti * 16 + l15;
      bf16x8 xa0 = *(const bf16x8*)(smem + swzA(col, g * 16));
      bf16x8 xa1 = *(const bf16x8*)(smem + swzA(col, 64 + g * 16));
#pragma unroll
      for (int ot = 0; ot < 4; ++ot) {
        f32x4 d = {0.f, 0.f, 0.f, 0.f};
        d = __builtin_amdgcn_mfma_f32_16x16x32_bf16(xa0, A1[ot][0], d, 0, 0, 0);
        d = __builtin_amdgcn_mfma_f32_16x16x32_bf16(xa1, A1[ot][1], d, 0, 0, 0);
        acc[cti][ot] = d;
      }
    }
    // scatter X3 -> X3s[c][t=w][u]: lane holds 4 consecutive u -> packed b64
#pragma unroll
    for (int cti = 0; cti < 2; ++cti) {
      int u0 = cti * 16 + g * 4;
#pragma unroll
      for (int ot = 0; ot < 4; ++ot) {
        int c = ot * 16 + l15;
        if (!cti || g < 2) {
          bf16x4v pk;
          pk[0] = (__bf16)acc[cti][ot][0];
          pk[1] = (__bf16)acc[cti][ot][1];
          pk[2] = (__bf16)acc[cti][ot][2];
          pk[3] = (__bf16)acc[cti][ot][3];
          *(bf16x4v*)(smem + swzB(c, w, 2 * u0)) = pk;
        } else if (g == 2) {  // u=24 only
          *(__bf16*)(smem + swzB(c, w, 48)) = (__bf16)acc[cti][ot][0];
        }
      }
    }
    // bias row u=25
    if (tid < 512) {
      int c = tid >> 3, t = tid & 7;
      *(__bf16*)(smem + swzB(c, t, 50)) = (__bf16)b3[s * 64 + c];
    }
    // B2 frags (a_ext), issued before barrier
    bf16x8 B2[8][2];
    const unsigned char* af = afrag + (size_t)(s * 16 + n) * 131072;
#pragma unroll
    for (int cc = 0; cc < 8; ++cc) {
      int c = w * 8 + cc;
#pragma unroll
      for (int vt = 0; vt < 2; ++vt)
        B2[cc][vt] = *(const bf16x8*)(af + ((c * 2 + vt) * 64 + l) * 16);
    }
    __syncthreads();
    // GEMM2: z[t][v] += X3s[c] . a_ext[c] (M rows 8..15 duplicate t0..7, discarded)
#pragma unroll
    for (int cc = 0; cc < 8; ++cc) {
      int c = w * 8 + cc;
      bf16x8 a2 = *(const bf16x8*)(smem + swzB(c, l15 & 7, g * 16));
      zacc[cc][0] = __builtin_amdgcn_mfma_f32_16x16x32_bf16(a2, B2[cc][0], zacc[cc][0], 0, 0, 0);
      zacc[cc][1] = __builtin_amdgcn_mfma_f32_16x16x32_bf16(a2, B2[cc][1], zacc[cc][1], 0, 0, 0);
    }
  }
  __syncthreads();  // all LDS reads done; whole smem becomes zs f32 [64][200]
  float* zs = (float*)smem;
  if (g < 2) {
#pragma unroll
    for (int cc = 0; cc < 8; ++cc) {
      int c = w * 8 + cc;
#pragma unroll
      for (int vt = 0; vt < 2; ++vt) {
        int v = vt * 16 + l15;
        if (v < 25) {
#pragma unroll
          for (int jj = 0; jj < 4; ++jj)
            zs[c * 200 + (g * 4 + jj) * 25 + v] = zacc[cc][vt][jj];
        }
      }
    }
  }
  __syncthreads();
  float4* yg4 = (float4*)(y + (size_t)n * kC * kTV);
  for (int i4 = tid; i4 < 3200; i4 += 512) {
    int c = i4 / 50, r4 = i4 % 50;
    float4 xv = xg4[c * 3200 + tb * 50 + r4];
    f32x4 zv = *(const f32x4*)(zs + c * 200 + r4 * 4);
    float4 o;
    o.x = fmaxf(zv[0] + xv.x, 0.f);
    o.y = fmaxf(zv[1] + xv.y, 0.f);
    o.z = fmaxf(zv[2] + xv.z, 0.f);
    o.w = fmaxf(zv[3] + xv.w, 0.f);
    yg4[c * 3200 + tb * 50 + r4] = o;
  }
}

extern "C" void kernel_launch(void* const* d_in, const int* in_sizes, int n_in,
                              void* d_out, int out_size, void* d_ws, size_t ws_size,
                              hipStream_t stream) {
  const float* x = (const float*)d_in[0];
  const float* Ag = (const float*)d_in[1];
  const float* alpha = (const float*)d_in[2];
  const float* w1 = (const float*)d_in[3];
  const float* b1 = (const float*)d_in[4];
  const float* w2 = (const float*)d_in[5];
  const float* b2 = (const float*)d_in[6];
  const float* w3 = (const float*)d_in[7];
  const float* b3 = (const float*)d_in[8];
  const float* w4 = (const float*)d_in[9];
  const float* b4 = (const float*)d_in[10];
  const int* sparse = (const int*)d_in[11];

  unsigned char* ws = (unsigned char*)d_ws;
  float* xm = (float*)ws;  // [16][64][25] f32 at offset 0
  float* y = (float*)d_out;

  hipFuncSetAttribute((const void*)k3_main,
                      hipFuncAttributeMaxDynamicSharedMemorySize, 65536);

  k1_mean<<<kN * kC, 256, 0, stream>>>(x, xm);
  k2_attn<<<kS * kN * 4, 256, 0, stream>>>(xm, Ag, alpha, w1, b1, w2, b2, w3, w4,
                                           b4, sparse, ws);
  dim3 g3(kN, kT / 8);
  k3_main<<<g3, 512, 65536, stream>>>(x, b3, ws, y);
}

// Round 7
// 86.953 us; speedup vs baseline: 1.6893x; 1.6893x over previous
//
#include <hip/hip_runtime.h>
#include <cmath>

typedef __bf16 bf16x4v __attribute__((ext_vector_type(4)));
typedef __bf16 bf16x8 __attribute__((ext_vector_type(8)));
typedef float f32x4 __attribute__((ext_vector_type(4)));

namespace {
constexpr int kN = 16, kC = 64, kT = 512, kV = 25, kS = 3, kO = 64;
constexpr int kTV = kT * kV;  // 12800
// ws layout (bytes): xm f32[25600 f] | afrag[48][8192][16] | w3f[3][512][16]
constexpr size_t WS_AFRAG = 102400;
constexpr size_t WS_W3F = WS_AFRAG + (size_t)48 * 131072;  // 6,393,856
}  // namespace

// XsT: bf16 [col=(t*32+u) 256][c' 64] swizzled, bytes [0, 32768)
__device__ __forceinline__ int swzA(int col, int cbyte) {
  return ((col << 7) + cbyte) ^ ((col & 7) << 4);
}
// X3s: bf16 [c 64][t 8][u 32] swizzled with ((c^t)&7) XOR, bytes [32768, 65536)
__device__ __forceinline__ int swzB(int c, int t, int ubyte) {
  return 32768 + (c << 9) + (((t << 6) + ubyte) ^ ((((c ^ t) & 7)) << 4));
}

// ---- k1: xm[n,c,v] = mean_t x[n,c,t,v] (phase-class accumulation, coalesced)
__global__ __launch_bounds__(256) void k1_mean(const float* __restrict__ x,
                                               float* __restrict__ xm) {
  const int bid = blockIdx.x;  // n*64 + c
  __shared__ float part[250][4];
  const int tid = threadIdx.x;
  const float4* xg4 = (const float4*)(x + (size_t)bid * kTV);
  if (tid < 250) {
    float a0 = 0.f, a1 = 0.f, a2 = 0.f, a3 = 0.f;
    for (int j = tid; j < 3200; j += 250) {  // j%250==tid -> const v-phase
      float4 v = xg4[j];
      a0 += v.x; a1 += v.y; a2 += v.z; a3 += v.w;
    }
    part[tid][0] = a0; part[tid][1] = a1; part[tid][2] = a2; part[tid][3] = a3;
  }
  __syncthreads();
  if (tid < 25) {
    float s = 0.f;
#pragma unroll
    for (int r = 0; r < 4; ++r) {
      int q = ((tid - r + 25) % 25) * 19 % 25;
#pragma unroll
      for (int p = 0; p < 10; ++p) s += part[q + 25 * p][r];
    }
    xm[bid * 25 + tid] = s * (1.f / 512.f);
  }
}

// ---- k2: a_frag (bf16, MFMA-B order, bias/colsum folded) + w3 frags
__global__ __launch_bounds__(256) void k2_attn(
    const float* __restrict__ xm, const float* __restrict__ Ag,
    const float* __restrict__ alpha, const float* __restrict__ w1,
    const float* __restrict__ b1, const float* __restrict__ w2,
    const float* __restrict__ b2, const float* __restrict__ w3,
    const float* __restrict__ w4, const float* __restrict__ b4,
    const int* __restrict__ sparse, unsigned char* __restrict__ ws) {
  const float thr = (float)sparse[0];
  const int b = blockIdx.x;
  const int s = b >> 6, n = (b >> 2) & 15, q = b & 3;
  __shared__ float xm_l[1600];
  __shared__ float x1_l[200], x2_l[200];
  __shared__ float att_l[8 * 625];
  __shared__ float attsum_l[200];
  __shared__ float ag_l[625];
  __shared__ float acs_l[25];
  __shared__ float w4_l[512];
  const int tid = threadIdx.x;
  for (int i = tid; i < 1600; i += 256) xm_l[i] = xm[n * 1600 + i];
  for (int i = tid; i < 512; i += 256) {
    float w = w4[s * 512 + i];
    w4_l[i] = (fabsf(w) > thr) ? w : 0.f;
  }
  for (int i = tid; i < 625; i += 256) ag_l[i] = Ag[s * 625 + i];
  __syncthreads();
  for (int i = tid; i < 400; i += 256) {
    int which = i / 200, idx = i % 200, r = idx / 25, u = idx % 25;
    const float* wrow = (which == 0 ? w1 : w2) + (s * 8 + r) * 64;
    float acc = 0.f;
    for (int cc = 0; cc < 64; ++cc) {
      float w = wrow[cc];
      w = (fabsf(w) > thr) ? w : 0.f;
      acc += w * xm_l[cc * 25 + u];
    }
    acc += (which == 0 ? b1 : b2)[s * 8 + r];
    if (which == 0) x1_l[idx] = acc;
    else x2_l[idx] = acc;
  }
  __syncthreads();
  for (int i = tid; i < 8 * 625; i += 256) {
    int r = i / 625, uv = i % 625, u = uv / 25, v = uv % 25;
    att_l[i] = tanhf(x1_l[r * 25 + u] - x2_l[r * 25 + v]);
  }
  __syncthreads();
  if (tid < 200) {
    int r = tid / 25, v = tid % 25;
    float sum = 0.f;
    for (int u = 0; u < 25; ++u) sum += att_l[r * 625 + u * 25 + v];
    attsum_l[tid] = sum;
  } else if (tid < 225) {
    int v = tid - 200;
    float sum = 0.f;
    for (int u = 0; u < 25; ++u) sum += ag_l[u * 25 + v];
    acs_l[v] = sum;
  }
  __syncthreads();
  const float al = alpha[0];
  // a_ext[c][u][v]: u<25 -> a ; u==25 -> colsum(a) (bias-fold) ; u>25 -> 0
  unsigned char* afrag = ws + WS_AFRAG + (size_t)(s * 16 + n) * 131072;
  for (int slot = q * 2048 + tid; slot < (q + 1) * 2048; slot += 256) {
    int c = slot >> 7, vt = (slot >> 6) & 1, l = slot & 63;
    int v = vt * 16 + (l & 15), g = l >> 4;
    bf16x8 out;
    if (v < 25) {
      float b4v = b4[s * 64 + c];
#pragma unroll
      for (int j = 0; j < 8; ++j) {
        int u = g * 8 + j;
        float val = 0.f;
        if (u < 25) {
          float acc = 0.f;
#pragma unroll
          for (int r = 0; r < 8; ++r) acc += w4_l[c * 8 + r] * att_l[r * 625 + u * 25 + v];
          val = al * (acc + b4v) + ag_l[u * 25 + v];
        } else if (u == 25) {
          float acc = 0.f;
#pragma unroll
          for (int r = 0; r < 8; ++r) acc += w4_l[c * 8 + r] * attsum_l[r * 25 + v];
          val = al * acc + 25.f * al * b4v + acs_l[v];
        }
        out[j] = (__bf16)val;
      }
    } else {
#pragma unroll
      for (int j = 0; j < 8; ++j) out[j] = (__bf16)0.f;
    }
    *(bf16x8*)(afrag + (size_t)slot * 16) = out;
  }
  // w3 frags
  if (n == 0 && tid < 128) {
    unsigned char* w3f = ws + WS_W3F + (size_t)s * 8192;
    int slot = q * 128 + tid;
    int ot = slot >> 7, ks = (slot >> 6) & 1, l = slot & 63;
    int o = ot * 16 + (l & 15), g = l >> 4;
    bf16x8 out;
#pragma unroll
    for (int j = 0; j < 8; ++j) {
      int cp = ks * 32 + g * 8 + j;
      float w = w3[(s * 64 + o) * 64 + cp];
      out[j] = (__bf16)((fabsf(w) > thr) ? w : 0.f);
    }
    *(bf16x8*)(w3f + slot * 16) = out;
  }
}

// ---- k3: TT=8, 64 KB LDS, 2 blocks/CU. stage -> GEMM1 -> X3s -> GEMM2 -> zs -> relu
__global__ __launch_bounds__(512) void k3_main(const float* __restrict__ x,
                                               const float* __restrict__ b3,
                                               const unsigned char* __restrict__ ws,
                                               float* __restrict__ y) {
  const int n = blockIdx.x;   // linear%8 == n%8 -> same-n blocks share XCD
  const int tb = blockIdx.y;  // 0..63 (8-t chunks)
  extern __shared__ __align__(16) unsigned char smem[];  // 65536
  const int tid = threadIdx.x;
  const int w = tid >> 6, l = tid & 63, g = l >> 4, l15 = l & 15;
  const float4* xg4 = (const float4*)(x + (size_t)n * kC * kTV);

  // zero XsT pad cols u=25..31 (b128 granules): 56 cols x 8 chunks
  for (int idx = tid; idx < 448; idx += 512) {
    int col_i = idx >> 3, gb = idx & 7;
    int t = col_i / 7, u = 25 + col_i % 7;
    f32x4 z = {0.f, 0.f, 0.f, 0.f};
    *(f32x4*)(smem + swzA(t * 32 + u, gb * 16)) = z;
  }
  // zero X3s pad u=26..31 (3 b32 per (c,t))
  for (int idx = tid; idx < 1536; idx += 512) {
    int pair = idx / 3, k = idx % 3;
    int c = pair >> 3, t = pair & 7;
    *(unsigned int*)(smem + swzB(c, t, 52 + 4 * k)) = 0u;
  }
  // stage x f32 -> XsT bf16 (coalesced f4 reads, b16 scatter)
  for (int i4 = tid; i4 < 3200; i4 += 512) {
    int c = i4 / 50, r4 = i4 % 50;
    float4 vv = xg4[c * 3200 + tb * 50 + r4];
    float vals[4] = {vv.x, vv.y, vv.z, vv.w};
    int lin = r4 * 4;
#pragma unroll
    for (int k = 0; k < 4; ++k) {
      int t = (lin + k) / 25, u = (lin + k) % 25;
      *(__bf16*)(smem + swzA(t * 32 + u, c * 2)) = (__bf16)vals[k];
    }
  }
  __syncthreads();

  const unsigned char* afrag = ws + WS_AFRAG;
  const unsigned char* w3f = ws + WS_W3F;

  f32x4 zacc[8][2];
#pragma unroll
  for (int cc = 0; cc < 8; ++cc)
#pragma unroll
    for (int vt = 0; vt < 2; ++vt) {
      f32x4 zz = {0.f, 0.f, 0.f, 0.f};
      zacc[cc][vt] = zz;
    }

  for (int s = 0; s < kS; ++s) {
    bf16x8 A1[4][2];
#pragma unroll
    for (int ot = 0; ot < 4; ++ot)
#pragma unroll
      for (int ks = 0; ks < 2; ++ks)
        A1[ot][ks] = *(const bf16x8*)(w3f + s * 8192 + ((ot * 2 + ks) * 64 + l) * 16);
    if (s) __syncthreads();  // GEMM2(s-1) X3s reads done before scatter overwrite

    // GEMM1 (swapped): D1[col][o]; wave w owns cols [32w, 32w+32)
    f32x4 acc[2][4];
#pragma unroll
    for (int cti = 0; cti < 2; ++cti) {
      int col = w * 32 + cti * 16 + l15;
      bf16x8 xa0 = *(const bf16x8*)(smem + swzA(col, g * 16));
      bf16x8 xa1 = *(const bf16x8*)(smem + swzA(col, 64 + g * 16));
#pragma unroll
      for (int ot = 0; ot < 4; ++ot) {
        f32x4 d = {0.f, 0.f, 0.f, 0.f};
        d = __builtin_amdgcn_mfma_f32_16x16x32_bf16(xa0, A1[ot][0], d, 0, 0, 0);
        d = __builtin_amdgcn_mfma_f32_16x16x32_bf16(xa1, A1[ot][1], d, 0, 0, 0);
        acc[cti][ot] = d;
      }
    }
    // scatter X3 -> X3s[c][t=w][u]: lane holds 4 consecutive u -> packed b64
#pragma unroll
    for (int cti = 0; cti < 2; ++cti) {
      int u0 = cti * 16 + g * 4;
#pragma unroll
      for (int ot = 0; ot < 4; ++ot) {
        int c = ot * 16 + l15;
        if (!cti || g < 2) {
          bf16x4v pk;
          pk[0] = (__bf16)acc[cti][ot][0];
          pk[1] = (__bf16)acc[cti][ot][1];
          pk[2] = (__bf16)acc[cti][ot][2];
          pk[3] = (__bf16)acc[cti][ot][3];
          *(bf16x4v*)(smem + swzB(c, w, 2 * u0)) = pk;
        } else if (g == 2) {  // u=24 only
          *(__bf16*)(smem + swzB(c, w, 48)) = (__bf16)acc[cti][ot][0];
        }
      }
    }
    // bias row u=25
    {
      int c = tid >> 3, t = tid & 7;
      *(__bf16*)(smem + swzB(c, t, 50)) = (__bf16)b3[s * 64 + c];
    }
    const unsigned char* af = afrag + (size_t)(s * 16 + n) * 131072;
    // prefetch first channel's a_ext frags (low liveness pipeline)
    bf16x8 b2cur0 = *(const bf16x8*)(af + ((w * 8 * 2 + 0) * 64 + l) * 16);
    bf16x8 b2cur1 = *(const bf16x8*)(af + ((w * 8 * 2 + 1) * 64 + l) * 16);
    __syncthreads();
    // GEMM2: z[t][v] += X3s[c] . a_ext[c] (M rows 8..15 duplicate t0..7, discarded)
#pragma unroll
    for (int cc = 0; cc < 8; ++cc) {
      int c = w * 8 + cc;
      bf16x8 b2n0, b2n1;
      if (cc < 7) {
        b2n0 = *(const bf16x8*)(af + (((c + 1) * 2 + 0) * 64 + l) * 16);
        b2n1 = *(const bf16x8*)(af + (((c + 1) * 2 + 1) * 64 + l) * 16);
      }
      bf16x8 a2 = *(const bf16x8*)(smem + swzB(c, l15 & 7, g * 16));
      zacc[cc][0] = __builtin_amdgcn_mfma_f32_16x16x32_bf16(a2, b2cur0, zacc[cc][0], 0, 0, 0);
      zacc[cc][1] = __builtin_amdgcn_mfma_f32_16x16x32_bf16(a2, b2cur1, zacc[cc][1], 0, 0, 0);
      if (cc < 7) {
        b2cur0 = b2n0;
        b2cur1 = b2n1;
      }
    }
  }
  __syncthreads();  // all LDS reads done; whole smem becomes zs f32 [64][200]
  float* zs = (float*)smem;
  if (g < 2) {
#pragma unroll
    for (int cc = 0; cc < 8; ++cc) {
      int c = w * 8 + cc;
#pragma unroll
      for (int vt = 0; vt < 2; ++vt) {
        int v = vt * 16 + l15;
        if (v < 25) {
#pragma unroll
          for (int jj = 0; jj < 4; ++jj)
            zs[c * 200 + (g * 4 + jj) * 25 + v] = zacc[cc][vt][jj];
        }
      }
    }
  }
  __syncthreads();
  float4* yg4 = (float4*)(y + (size_t)n * kC * kTV);
  for (int i4 = tid; i4 < 3200; i4 += 512) {
    int c = i4 / 50, r4 = i4 % 50;
    float4 xv = xg4[c * 3200 + tb * 50 + r4];
    f32x4 zv = *(const f32x4*)(zs + c * 200 + r4 * 4);
    float4 o;
    o.x = fmaxf(zv[0] + xv.x, 0.f);
    o.y = fmaxf(zv[1] + xv.y, 0.f);
    o.z = fmaxf(zv[2] + xv.z, 0.f);
    o.w = fmaxf(zv[3] + xv.w, 0.f);
    yg4[c * 3200 + tb * 50 + r4] = o;
  }
}

extern "C" void kernel_launch(void* const* d_in, const int* in_sizes, int n_in,
                              void* d_out, int out_size, void* d_ws, size_t ws_size,
                              hipStream_t stream) {
  const float* x = (const float*)d_in[0];
  const float* Ag = (const float*)d_in[1];
  const float* alpha = (const float*)d_in[2];
  const float* w1 = (const float*)d_in[3];
  const float* b1 = (const float*)d_in[4];
  const float* w2 = (const float*)d_in[5];
  const float* b2 = (const float*)d_in[6];
  const float* w3 = (const float*)d_in[7];
  const float* b3 = (const float*)d_in[8];
  const float* w4 = (const float*)d_in[9];
  const float* b4 = (const float*)d_in[10];
  const int* sparse = (const int*)d_in[11];

  unsigned char* ws = (unsigned char*)d_ws;
  float* xm = (float*)ws;  // [16][64][25] f32 at offset 0
  float* y = (float*)d_out;

  hipFuncSetAttribute((const void*)k3_main,
                      hipFuncAttributeMaxDynamicSharedMemorySize, 65536);

  k1_mean<<<kN * kC, 256, 0, stream>>>(x, xm);
  k2_attn<<<kS * kN * 4, 256, 0, stream>>>(xm, Ag, alpha, w1, b1, w2, b2, w3, w4,
                                           b4, sparse, ws);
  dim3 g3(kN, kT / 8);
  k3_main<<<g3, 512, 65536, stream>>>(x, b3, ws, y);
}